// Round 13
// baseline (214.130 us; speedup 1.0000x reference)
//
#include <hip/hip_runtime.h>
#include <math.h>

#define B_ 16
#define T_ 12
#define N_ 1024
#define D_ 64
#define HS_ 16
#define HT_ 64
#define TT_ 192
#define BT_ 192

typedef _Float16 f16x2 __attribute__((ext_vector_type(2)));

__device__ __forceinline__ unsigned int pkrtz(float a, float b){
    auto r = __builtin_amdgcn_cvt_pkrtz(a, b);
    return __builtin_bit_cast(unsigned int, r);
}
__device__ __forceinline__ float fdot2u(unsigned int a, unsigned int b, float c){
    return __builtin_amdgcn_fdot2(__builtin_bit_cast(f16x2, a),
                                  __builtin_bit_cast(f16x2, b), c, false);
}
__device__ __forceinline__ float loF(unsigned int a){ f16x2 h = __builtin_bit_cast(f16x2, a); return (float)h.x; }
__device__ __forceinline__ float hiF(unsigned int a){ f16x2 h = __builtin_bit_cast(f16x2, a); return (float)h.y; }

__device__ __forceinline__ float lrelu_(float v){ return v > 0.f ? v : 0.01f*v; }
__device__ __forceinline__ float squash_sc(float sn){ return (sn/(1.f+sn))/(sqrtf(sn)+1e-8f); }

__device__ __forceinline__ float wredsum64(float v){
    #pragma unroll
    for (int mk = 1; mk < 64; mk <<= 1) v += __shfl_xor(v, mk, 64);
    return v;
}

// ---------------------------------------------------------------------------
// k_wpack: Wpk2[d*32+j] = f16pair(Wp[d][2j], Wp[d][2j+1])   1 block x 256
// ---------------------------------------------------------------------------
__global__ __launch_bounds__(256) void k_wpack(const float* __restrict__ Wp,
        unsigned int* __restrict__ Wpk2){
    int t = threadIdx.x;
    #pragma unroll
    for (int i = 0; i < 8; ++i){
        int idx = i*256 + t;
        float2 w2 = *(const float2*)(Wp + 2*idx);
        Wpk2[idx] = pkrtz(w2.x, w2.y);
    }
}

// ---------------------------------------------------------------------------
// k_P: P = squash(x@W^T+b) -> f16 d-pairs Ppk[bt][n][32]   grid (192,4) x 256
// Lane-per-row, fully unrolled (rule #20: partial unroll -> scratch).
// ---------------------------------------------------------------------------
__global__ __launch_bounds__(256, 1) void k_P(const float* __restrict__ x,
        const unsigned int* __restrict__ Wpk2, const float* __restrict__ bp,
        unsigned int* __restrict__ Ppk){
    __shared__ unsigned int xst[4][64*33];
    int w = threadIdx.x >> 6, l = threadIdx.x & 63;
    size_t rbase = (size_t)blockIdx.x*1024 + blockIdx.y*256 + w*64;
    const float* xb = x + rbase*64;
    #pragma unroll
    for (int j = 0; j < 32; ++j){
        int idx = j*64 + l;
        int row = idx >> 5, cp = idx & 31;
        float2 xv = *(const float2*)(xb + row*64 + 2*cp);
        xst[w][row*33 + cp] = pkrtz(xv.x, xv.y);
    }
    unsigned int xr[32];
    #pragma unroll
    for (int j = 0; j < 32; ++j) xr[j] = xst[w][l*33 + j];

    float sn = 0.f;
    unsigned int ypk[32];
    #pragma unroll
    for (int d2 = 0; d2 < 32; ++d2){
        float y0 = bp[2*d2], y1 = bp[2*d2+1];
        float y0b = 0.f, y1b = 0.f;
        const uint4* wr0 = (const uint4*)(Wpk2 + (2*d2)*32);
        const uint4* wr1 = (const uint4*)(Wpk2 + (2*d2+1)*32);
        #pragma unroll
        for (int jq = 0; jq < 8; ++jq){
            uint4 w0 = wr0[jq], w1 = wr1[jq];
            uint4 xa = *(uint4*)&xr[4*jq];
            y0  = fdot2u(xa.x, w0.x, y0);  y0b = fdot2u(xa.y, w0.y, y0b);
            y0  = fdot2u(xa.z, w0.z, y0);  y0b = fdot2u(xa.w, w0.w, y0b);
            y1  = fdot2u(xa.x, w1.x, y1);  y1b = fdot2u(xa.y, w1.y, y1b);
            y1  = fdot2u(xa.z, w1.z, y1);  y1b = fdot2u(xa.w, w1.w, y1b);
        }
        float ya = y0 + y0b, yb = y1 + y1b;
        sn += ya*ya + yb*yb;
        ypk[d2] = pkrtz(ya, yb);
    }
    float sc = squash_sc(sn);
    #pragma unroll
    for (int d2 = 0; d2 < 32; ++d2)
        ypk[d2] = pkrtz(loF(ypk[d2])*sc, hiF(ypk[d2])*sc);
    unsigned int* pb = Ppk + (rbase + l)*32;
    #pragma unroll
    for (int q = 0; q < 8; ++q)
        ((uint4*)pb)[q] = *(uint4*)&ypk[4*q];
}

// ---------------------------------------------------------------------------
// kA: one routing sweep over an n-chunk of 128.  grid (192,8) x 256
// (modes as before; dadj inline in MODE 0, consumed in MODE 3)
// ---------------------------------------------------------------------------
template<int MODE>
__global__ __launch_bounds__(256, 2) void kA(const unsigned int* __restrict__ Ppk,
        const float* __restrict__ teb, const float* __restrict__ adj,
        float* __restrict__ dadjb,
        const float* __restrict__ tpIn, const float* __restrict__ spart,
        float* __restrict__ v1buf, const float* __restrict__ vsumIn,
        float* __restrict__ vsumOut,
        float* __restrict__ tpOut, float* __restrict__ spOut,
        float* __restrict__ cout){
    __shared__ unsigned int PL[128*36];
    __shared__ unsigned int vLp[16*36];
    __shared__ float bL[16*130];
    __shared__ float cL[128*20];
    int bt = blockIdx.x, ch = blockIdx.y;
    int t = threadIdx.x, w = t >> 6, l = t & 63;
    int n0 = ch*128;

    const uint4* Pg = (const uint4*)(Ppk + ((size_t)bt*1024 + n0)*32);
    #pragma unroll
    for (int k = 0; k < 4; ++k){
        int idx4 = t + 256*k;
        uint4 u = Pg[idx4];
        *(uint4*)&PL[(idx4 >> 3)*36 + 4*(idx4 & 7)] = u;
    }
    if (MODE != 0){
        float sp = 0.f;
        if (MODE == 1){
            #pragma unroll
            for (int c = 0; c < 8; ++c) sp += spart[((size_t)bt*8 + c)*64 + l];
            sp *= (1.f/16.f);
        }
        #pragma unroll
        for (int i = 0; i < 4; ++i){
            int h = 4*w + i;
            float s = 0.f;
            #pragma unroll
            for (int c = 0; c < 8; ++c)
                s += tpIn[(((size_t)bt*8 + c)*16 + h)*64 + l];
            size_t oi = ((size_t)bt*16 + h)*64 + l;
            float vs;
            if (MODE == 1){
                float sn = wredsum64(s*s);
                float v1 = s*squash_sc(sn);
                v1buf[oi] = v1;
                float q = v1*sp;
                float sn2 = wredsum64(q*q);
                vs = q*squash_sc(sn2);
            } else {
                float q = v1buf[oi]*s;
                float sn = wredsum64(q*q);
                vs = vsumIn[oi] + q*squash_sc(sn);
            }
            if (MODE != 3) vsumOut[oi] = vs;
            float vo = __shfl_xor(vs, 1, 64);
            if (!(l & 1)) vLp[h*36 + (l >> 1)] = pkrtz(vs, vo);
        }
    }
    __syncthreads();

    {
        int n = t & 127, hg = t >> 7;
        float acc8[8];
        #pragma unroll
        for (int i = 0; i < 8; ++i) acc8[i] = 0.f;
        if (MODE != 0){
            #pragma unroll
            for (int j = 0; j < 8; ++j){
                uint4 pq = *(uint4*)&PL[n*36 + 4*j];
                #pragma unroll
                for (int i = 0; i < 8; ++i){
                    uint4 vq = *(uint4*)&vLp[(hg*8 + i)*36 + 4*j];
                    acc8[i] = fdot2u(pq.x, vq.x, acc8[i]);
                    acc8[i] = fdot2u(pq.y, vq.y, acc8[i]);
                    acc8[i] = fdot2u(pq.z, vq.z, acc8[i]);
                    acc8[i] = fdot2u(pq.w, vq.w, acc8[i]);
                }
            }
        }
        if (MODE == 0){
            float tl[16];
            #pragma unroll
            for (int e = 0; e < 16; ++e) tl[e] = teb[bt*16 + e];
            #pragma unroll
            for (int i = 0; i < 8; ++i){
                int h = hg*8 + i;
                float s = 0.f;
                #pragma unroll
                for (int e = 0; e < 16; ++e)
                    s += tl[e]*adj[(((e << 4) + h) << 10) + n0 + n];
                acc8[i] = s;
                dadjb[((size_t)bt*16 + h)*1024 + n0 + n] = s;
            }
        }
        if (MODE == 3){
            #pragma unroll
            for (int i = 0; i < 8; ++i)
                acc8[i] += dadjb[((size_t)bt*16 + hg*8 + i)*1024 + n0 + n];
        }
        #pragma unroll
        for (int i = 0; i < 8; ++i) bL[(hg*8 + i)*130 + n] = acc8[i];
    }
    __syncthreads();

    if (t < 128){
        int n = t;
        float M = -1e30f;
        #pragma unroll
        for (int h = 0; h < 16; ++h) M = fmaxf(M, bL[h*130 + n]);
        float S = 0.f; float ev[16];
        #pragma unroll
        for (int h = 0; h < 16; ++h){ ev[h] = __expf(bL[h*130 + n] - M); S += ev[h]; }
        float inv = 1.f/S;
        #pragma unroll
        for (int h = 0; h < 16; ++h){
            float cv = ev[h]*inv;
            cL[n*20 + h] = cv;
            if (MODE == 3) cout[((size_t)bt*16 + h)*1024 + n0 + n] = cv;
        }
    }
    __syncthreads();

    float acc[4] = {0.f,0.f,0.f,0.f};
    float sp2 = 0.f;
    #pragma unroll 2
    for (int n = 0; n < 128; ++n){
        unsigned int pv = PL[n*36 + (l >> 1)];
        float p = (l & 1) ? hiF(pv) : loF(pv);
        float4 c4 = *(float4*)&cL[n*20 + 4*w];
        acc[0] += c4.x*p; acc[1] += c4.y*p; acc[2] += c4.z*p; acc[3] += c4.w*p;
        if (MODE == 0) sp2 += p;
    }
    #pragma unroll
    for (int i = 0; i < 4; ++i)
        tpOut[(((size_t)bt*8 + ch)*16 + 4*w + i)*64 + l] = acc[i];
    if (MODE == 0 && w == 0)
        spOut[((size_t)bt*8 + ch)*64 + l] = sp2;
}

// k_s: s = reduce tpart (raw)   grid 192 x 256
__global__ __launch_bounds__(256) void k_s(const float* __restrict__ tpart,
        float* __restrict__ sout){
    int bt = blockIdx.x;
    int w = threadIdx.x >> 6, l = threadIdx.x & 63;
    #pragma unroll
    for (int i = 0; i < 4; ++i){
        int h = 4*w + i;
        float s = 0.f;
        #pragma unroll
        for (int c = 0; c < 8; ++c)
            s += tpart[(((size_t)bt*8 + c)*16 + h)*64 + l];
        sout[((size_t)bt*16 + h)*64 + l] = s;
    }
}

// ---------------------------------------------------------------------------
// k_wsp: precompute w_sp/b_sp per node.  grid (8,32) x 256
// ROUND-12 BUG FIX: neL is 512 entries but was loaded by only 256 threads
// (`neL[t&511]`) -> nodes 16-31 used garbage. Now 2x256 loads.
// ---------------------------------------------------------------------------
__global__ __launch_bounds__(256) void k_wsp(const float* __restrict__ ne,
        const float* __restrict__ wspa, const float* __restrict__ bspa,
        unsigned int* __restrict__ wpkg, float* __restrict__ bspg){
    __shared__ float wspaL[16*512];
    __shared__ float neL[32*16];
    int ioc = blockIdx.x, nc = blockIdx.y;
    int t = threadIdx.x, w = t >> 6, o = t & 63;
    #pragma unroll
    for (int k = 0; k < 8; ++k){
        int idx4 = t + 256*k;                 // 0..2047 float4s
        int e = idx4 >> 7, j4 = idx4 & 127;
        *(float4*)&wspaL[e*512 + 4*j4] =
            *(const float4*)(wspa + (size_t)e*4096 + ioc*512 + 4*j4);
    }
    #pragma unroll
    for (int k = 0; k < 2; ++k)
        neL[k*256 + t] = ne[(size_t)nc*512 + k*256 + t];
    __syncthreads();
    int c0 = (2*w)*64 + o, c1 = (2*w+1)*64 + o;
    #pragma unroll 2
    for (int n = 0; n < 32; ++n){
        float a0 = 0.f, a1 = 0.f;
        #pragma unroll
        for (int e = 0; e < 16; ++e){
            float nv = neL[n*16 + e];
            a0 += nv*wspaL[e*512 + c0];
            a1 += nv*wspaL[e*512 + c1];
        }
        wpkg[((size_t)(nc*32 + n))*2048 + (ioc*4 + w)*64 + o] = pkrtz(a0, a1);
    }
    if (ioc == 0){
        #pragma unroll
        for (int k = 0; k < 8; ++k){
            int idx = k*256 + t;              // 0..2047 -> n=idx>>6, o2=idx&63
            int n = idx >> 6, o2 = idx & 63;
            float a = 0.f;
            #pragma unroll
            for (int e = 0; e < 16; ++e)
                a += neL[n*16 + e]*bspa[e*64 + o2];
            bspg[(size_t)(nc*32 + n)*64 + o2] = a;
        }
    }
}

// k_dyntem: fused dyn + tem.  grid (16,64) x 256
__global__ __launch_bounds__(256) void k_dyntem(const float* __restrict__ timeb,
        const float* __restrict__ tadj, const float* __restrict__ sbuf,
        float* __restrict__ dyn, float* __restrict__ tem){
    __shared__ float dynL[192];
    __shared__ float part[4][64];
    int b = blockIdx.x, h = blockIdx.y, t = threadIdx.x;
    if (t < 192){
        float a = 0.f;
        #pragma unroll
        for (int e = 0; e < 16; ++e)
            a += timeb[b*16 + e]*tadj[((size_t)e*HT_ + h)*TT_ + t];
        dynL[t] = a;
        dyn[((size_t)b*HT_ + h)*TT_ + t] = a;
    }
    __syncthreads();
    int p = t >> 6, d = t & 63;
    const float* sb = sbuf + (size_t)b*TT_*64;
    float a = 0.f;
    #pragma unroll 4
    for (int k = 48*p; k < 48*p + 48; ++k)
        a += dynL[k]*(sb[(size_t)k*64 + d] + (float)((k >> 4) + 1)*(1.f/12.f));
    part[p][d] = a;
    __syncthreads();
    if (t < 64)
        tem[((size_t)b*HT_ + h)*64 + t] =
            lrelu_(part[0][t] + part[1][t] + part[2][t] + part[3][t]);
}

// ret=lrelu(sum_h dyn*tem)+s; v2=squash(ret)   grid (16,48) x 256
__global__ __launch_bounds__(256) void k_retv2(const float* __restrict__ dyn,
        const float* __restrict__ temb, const float* __restrict__ sbuf,
        float* __restrict__ v2){
    int b = blockIdx.x, kg = blockIdx.y;
    int w = threadIdx.x >> 6, l = threadIdx.x & 63;
    int k = kg*4 + w;
    const float* tb = temb + (size_t)b*HT_*64;
    float a0 = 0.f, a1 = 0.f;
    #pragma unroll 4
    for (int h = 0; h < HT_; h += 2){
        a0 += dyn[((size_t)b*HT_ + h  )*TT_ + k] * tb[(size_t)h*64 + l];
        a1 += dyn[((size_t)b*HT_ + h+1)*TT_ + k] * tb[(size_t)(h+1)*64 + l];
    }
    float a = lrelu_(a0 + a1);
    float r = a + sbuf[((size_t)b*TT_ + k)*64 + l];
    float sn = wredsum64(r*r);
    v2[((size_t)b*TT_ + k)*64 + l] = r*squash_sc(sn);
}

// recon f16 pairs, layout [n][bt][32]   grid (192,8) x 256
__global__ __launch_bounds__(256) void k_rec(const float* __restrict__ cbuf,
        const float* __restrict__ v2, unsigned int* __restrict__ recpk){
    __shared__ float vL[16*68];
    __shared__ float cL[16*132];
    int bt = blockIdx.x, nc = blockIdx.y;
    int t = threadIdx.x, l = t & 63, g = t >> 6;
    #pragma unroll
    for (int i = 0; i < 4; ++i){
        int idx = i*256 + t;
        vL[(idx>>6)*68 + (idx&63)] = v2[(size_t)bt*1024 + idx];
    }
    #pragma unroll
    for (int i = 0; i < 8; ++i){
        int idx = i*256 + t;
        cL[(idx>>7)*132 + (idx&127)] =
            cbuf[((size_t)bt*16 + (idx>>7))*1024 + nc*128 + (idx&127)];
    }
    __syncthreads();
    float vreg[16];
    #pragma unroll
    for (int h = 0; h < 16; ++h) vreg[h] = vL[h*68 + l];
    #pragma unroll 4
    for (int i = 0; i < 32; ++i){
        int nl = g + 4*i;
        float a = 0.f;
        #pragma unroll
        for (int h = 0; h < 16; ++h) a += cL[h*132 + nl]*vreg[h];
        float ap = __shfl_xor(a, 1, 64);
        if (!(l & 1))
            recpk[((size_t)(nc*128 + nl)*192 + bt)*32 + (l>>1)] = pkrtz(a, ap);
    }
}

// out = lrelu(rec @ wsp[n] + bsp[n] + x)   grid (1024,2) x 256
// wsp/bsp precomputed (k_wsp) -> 32 coalesced u32 loads, no compute phase.
__global__ __launch_bounds__(256) void k_final(const float* __restrict__ x,
        const unsigned int* __restrict__ wpkg, const float* __restrict__ bspg,
        const unsigned int* __restrict__ recpk, float* __restrict__ out){
    __shared__ __align__(16) unsigned int recL[96*32];
    int n = blockIdx.x, half = blockIdx.y;
    int t = threadIdx.x, l = t & 63, g = t >> 6;
    unsigned int wr[32];
    const unsigned int* wn = wpkg + (size_t)n*2048;
    #pragma unroll
    for (int ip = 0; ip < 32; ++ip) wr[ip] = wn[ip*64 + l];
    float bsp = bspg[(size_t)n*64 + l];
    {
        const uint4* src = (const uint4*)(recpk + ((size_t)n*192 + half*96)*32);
        #pragma unroll
        for (int k = 0; k < 3; ++k)
            ((uint4*)recL)[t + 256*k] = src[t + 256*k];
    }
    __syncthreads();
    #pragma unroll 2
    for (int i = 0; i < 24; ++i){
        int r = i*4 + g;
        int bt = half*96 + r;
        const uint4* rp = (const uint4*)&recL[r*32];
        float o0 = bsp, o1 = 0.f;
        #pragma unroll
        for (int jj = 0; jj < 8; ++jj){
            uint4 rq = rp[jj];
            o0 = fdot2u(rq.x, wr[4*jj+0], o0);
            o1 = fdot2u(rq.y, wr[4*jj+1], o1);
            o0 = fdot2u(rq.z, wr[4*jj+2], o0);
            o1 = fdot2u(rq.w, wr[4*jj+3], o1);
        }
        size_t oidx = ((size_t)bt*1024 + n)*64 + l;
        out[oidx] = lrelu_(o0 + o1 + x[oidx]);
    }
}

extern "C" void kernel_launch(void* const* d_in, const int* in_sizes, int n_in,
                              void* d_out, int out_size, void* d_ws, size_t ws_size,
                              hipStream_t stream) {
    const float* x     = (const float*)d_in[0];
    const float* ne    = (const float*)d_in[1];
    const float* timeb = (const float*)d_in[2];
    const float* teb   = (const float*)d_in[3];
    const float* Wp    = (const float*)d_in[4];
    const float* bp    = (const float*)d_in[5];
    const float* tadj  = (const float*)d_in[6];
    const float* adj   = (const float*)d_in[7];
    const float* wspa  = (const float*)d_in[8];
    const float* bspa  = (const float*)d_in[9];

    float* out    = (float*)d_out;
    float* outc   = out  + (size_t)BT_*N_*64;      // c:   [BT,HS,N]
    float* outdyn = outc + (size_t)BT_*HS_*N_;     // dyn: [B,HT,TT]

    char* ws = (char*)d_ws;
    unsigned int* Ppk  = (unsigned int*)ws;                          // 25.2 MB
    float* dadj  = (float*)(ws + 25165824);                          // 12.6 MB
    float* tpA   = dadj  + (size_t)BT_*HS_*N_;                       // 6.3 MB
    float* tpB   = tpA   + (size_t)BT_*8*HS_*64;                     // 6.3 MB
    float* spart = tpB   + (size_t)BT_*8*HS_*64;                     // 0.39 MB
    float* v1buf = spart + (size_t)BT_*8*64;
    float* vs0   = v1buf + (size_t)BT_*HS_*64;
    float* vs1   = vs0   + (size_t)BT_*HS_*64;
    float* sbuf  = vs1   + (size_t)BT_*HS_*64;
    float* temb  = sbuf  + (size_t)BT_*HS_*64;
    float* v2    = temb  + (size_t)B_*HT_*64;
    unsigned int* recpk = (unsigned int*)(v2 + (size_t)BT_*HS_*64);  // 25.2 MB
    unsigned int* Wpk2  = recpk + (size_t)N_*BT_*32;                 // 8 KB
    // wpkg/bspg alias dadj's region (dead after kA<3>; k_wsp launches after it)
    unsigned int* wpkg = (unsigned int*)dadj;                        // 8 MB
    float* bspg = (float*)(wpkg + (size_t)N_*2048);                  // 256 KB

    k_wpack<<<dim3(1), 256, 0, stream>>>(Wp, Wpk2);
    k_P<<<dim3(BT_, 4), 256, 0, stream>>>(x, Wpk2, bp, Ppk);

    // pass 0: logits = dadj (computed inline, stored); t partials + sumP chunks
    kA<0><<<dim3(BT_, 8), 256, 0, stream>>>(Ppk, teb, adj, dadj, nullptr,
            nullptr, nullptr, nullptr, nullptr, tpA, spart, nullptr);
    // iter1(fold)+iter2: prologue {v1, vr1=vs0}; c2; t2 -> tpB
    kA<1><<<dim3(BT_, 8), 256, 0, stream>>>(Ppk, teb, adj, dadj, tpA,
            spart, v1buf, nullptr, vs0, tpB, nullptr, nullptr);
    // iter3: prologue {v2; vs1=vs0+v2}; c3; t3 -> tpA
    kA<2><<<dim3(BT_, 8), 256, 0, stream>>>(Ppk, teb, adj, dadj, tpB,
            nullptr, v1buf, vs0, vs1, tpA, nullptr, nullptr);
    // final: prologue {v3; vs=vs1+v3}; c=softmax(vs.P+dadj) -> outc; s -> tpB
    kA<3><<<dim3(BT_, 8), 256, 0, stream>>>(Ppk, teb, adj, dadj, tpA,
            nullptr, v1buf, vs1, nullptr, tpB, nullptr, outc);
    k_s<<<dim3(BT_), 256, 0, stream>>>(tpB, sbuf);

    // dadj dead -> safe to overwrite with wsp/bsp precompute
    k_wsp<<<dim3(8, 32), 256, 0, stream>>>(ne, wspa, bspa, wpkg, bspg);

    k_dyntem<<<dim3(B_, HT_), 256, 0, stream>>>(timeb, tadj, sbuf, outdyn, temb);
    k_retv2<<<dim3(B_, 48), 256, 0, stream>>>(outdyn, temb, sbuf, v2);
    k_rec<<<dim3(BT_, 8), 256, 0, stream>>>(outc, v2, recpk);
    k_final<<<dim3(N_, 2), 256, 0, stream>>>(x, wpkg, bspg, recpk, out);
}